// Round 9
// baseline (150.445 us; speedup 1.0000x reference)
//
#include <hip/hip_runtime.h>
#include <stdint.h>

#define B_    8
#define N_    512
#define DIN   1024
#define DOUT  1024
#define L_    16
#define T_    4096

#define BM 128
#define BN 128
#define BK 32
#define NB (DOUT / BN)          /* 8 */
#define NKT (DIN / BK)          /* 32 K-tiles */
#define MT_MAX 320
#define ZROW ((long)B_ * N_)    /* zero-row index in pooled_bf16 */
#define GRID_GEMM 512           /* persistent: 2 blocks/CU */

typedef __attribute__((ext_vector_type(8))) short short8;
typedef __attribute__((ext_vector_type(4))) float f32x4;

#define POOLED_ELEMS ((long)B_ * N_ * DIN + DIN)
#define WS_W_OFF     ((size_t)POOLED_ELEMS * 2)
#define WS_META_OFF  (WS_W_OFF + (size_t)L_ * DOUT * DIN * 2)

__device__ __forceinline__ unsigned short f2bf(float f) {
  unsigned u = __float_as_uint(f);
  u += 0x7FFFu + ((u >> 16) & 1u);   /* RNE */
  return (unsigned short)(u >> 16);
}

__device__ __forceinline__ void gload_lds16(const void* g, void* l) {
  __builtin_amdgcn_global_load_lds(
      (const __attribute__((address_space(1))) void*)g,
      (__attribute__((address_space(3))) void*)l, 16, 0, 0);
}

__device__ __forceinline__ void bar() {
  asm volatile("" ::: "memory");
  __builtin_amdgcn_s_barrier();
  asm volatile("" ::: "memory");
}

/* ---------------- kernel 1: fp32 -> bf16 conversion ---------------- */
__global__ void k_convert(const float* __restrict__ pooled,
                          const float* __restrict__ W,
                          unsigned short* __restrict__ wsP,
                          unsigned short* __restrict__ wsW) {
  const long np4 = (long)B_ * N_ * DIN / 4;
  const long nw4 = (long)L_ * DOUT * DIN / 4;
  const long nz4 = DIN / 4;
  long i = (long)blockIdx.x * blockDim.x + threadIdx.x;
  const long stride = (long)gridDim.x * blockDim.x;
  for (; i < np4 + nw4 + nz4; i += stride) {
    if (i < np4) {
      float4 v = ((const float4*)pooled)[i];
      ushort4 o = { f2bf(v.x), f2bf(v.y), f2bf(v.z), f2bf(v.w) };
      ((ushort4*)wsP)[i] = o;
    } else if (i < np4 + nw4) {
      float4 v = ((const float4*)W)[i - np4];
      ushort4 o = { f2bf(v.x), f2bf(v.y), f2bf(v.z), f2bf(v.w) };
      ((ushort4*)wsW)[i - np4] = o;
    } else {
      ushort4 z = {0, 0, 0, 0};
      ((ushort4*)wsP)[i - nw4] = z;
    }
  }
}

/* ---------------- kernel 2: dedup prep + counter reset ----------------
   Entry = t(12) | n(10) | rep(8). Positions 0..14 of a segment unique
   (rep=1, group l=pos); positions >=15 share one output row -> group 15
   entries with rep (split at 255). Invalid t's -> zero-row (n=1023).    */
__global__ void k_prep(const int* __restrict__ pidx,
                       unsigned* __restrict__ tlist,
                       int* __restrict__ goff, int* __restrict__ grows,
                       unsigned* __restrict__ table, int* __restrict__ ntiles,
                       int* __restrict__ ctr) {
  __shared__ int sp[N_];
  __shared__ int cnt[L_], pos[L_];
  const int tid = threadIdx.x;          /* 512 threads, one per segment */
  if (tid < N_) sp[tid] = pidx[tid];
  if (tid < L_) cnt[tid] = 0;
  if (tid < 8) ctr[tid] = 0;            /* work-stealing counters */
  __syncthreads();

  int start = tid ? sp[tid - 1] + 1 : 0;
  int len = sp[tid] - start + 1;
  if (len < 0) len = 0;
  const int nfull = len < 15 ? len : 15;

  for (int l2 = 0; l2 < nfull; ++l2) atomicAdd(&cnt[l2], 1);
  if (len > 15) atomicAdd(&cnt[15], (len - 15 + 254) / 255);
  if (tid == N_ - 1) {
    int invlen = T_ - 1 - sp[N_ - 1];
    if (invlen > 0) atomicAdd(&cnt[15], (invlen + 254) / 255);
  }
  __syncthreads();
  if (tid == 0) {
    int off = 0;
    for (int l2 = 0; l2 < L_; ++l2) {
      pos[l2] = off; goff[l2] = off; grows[l2] = cnt[l2] * B_;
      off += cnt[l2];
    }
  }
  __syncthreads();

  for (int l2 = 0; l2 < nfull; ++l2) {
    int p = atomicAdd(&pos[l2], 1);
    tlist[p] = (unsigned)(start + l2) | ((unsigned)tid << 12) | (1u << 22);
  }
  if (len > 15) {
    int rem = len - 15, tt2 = start + 15;
    while (rem > 0) {
      int rr = rem > 255 ? 255 : rem;
      int p = atomicAdd(&pos[15], 1);
      tlist[p] = (unsigned)tt2 | ((unsigned)tid << 12) | ((unsigned)rr << 22);
      tt2 += rr; rem -= rr;
    }
  }
  if (tid == N_ - 1) {
    int tt2 = sp[N_ - 1] + 1;
    int rem = T_ - tt2;
    while (rem > 0) {
      int rr = rem > 255 ? 255 : rem;
      int p = atomicAdd(&pos[15], 1);
      tlist[p] = (unsigned)tt2 | (1023u << 12) | ((unsigned)rr << 22);
      tt2 += rr; rem -= rr;
    }
  }
  __syncthreads();
  if (tid == 0) {
    int tt = 0;
    for (int l2 = 0; l2 < L_; ++l2) {
      int rows = cnt[l2] * B_;
      for (int r0 = 0; r0 < rows; r0 += BM) table[tt++] = (unsigned)l2 | ((unsigned)r0 << 4);
    }
    *ntiles = tt;
  }
}

/* ---------------- kernel 3: persistent gather-GEMM, cross-tile pipeline ----
   128x128 tile, BK=32, 4 waves, wave 64x64 (R8's verified phase math).
   4 LDS buffers (64 KiB -> 2 blocks/CU), depth-3 prefetch (vmcnt(8)),
   persistent blocks + per-column work-stealing, phases 29..31 stage the
   NEXT tile's kt0..2 -> no per-tile drain bubble. Dedup rep-write epilogue. */
__global__ __launch_bounds__(256, 2)
void k_gemm(const unsigned short* __restrict__ wsP,
            const unsigned short* __restrict__ wsW,
            const unsigned* __restrict__ tlist,
            const int* __restrict__ goff,
            const int* __restrict__ grows,
            const unsigned* __restrict__ table,
            const int* __restrict__ ntiles,
            int* __restrict__ ctr,
            float* __restrict__ out) {
  const int nt = blockIdx.x & 7;     /* fixed N-column == XCD pin */
  const int NT = *ntiles;

  __shared__ __align__(16) unsigned short As[4][BM * BK];  /* 4 x 8 KiB */
  __shared__ __align__(16) unsigned short Bs[4][BN * BK];  /* 4 x 8 KiB */
  __shared__ int s_g;

  const int tid  = threadIdx.x;
  const int lane = tid & 63;
  const int w    = tid >> 6;      /* 0..3 */
  const int wm   = w >> 1;
  const int wn   = w & 1;

  const int srow = tid >> 2;                       /* 0..63 */
  const int sx4  = ((tid & 3) ^ ((srow >> 1) & 3)) * 16;

  /* first claim */
  if (tid == 0) s_g = atomicAdd(&ctr[nt], 1);
  __syncthreads();
  int mt = s_g;
  if (mt >= NT) return;

/* build gather/staging pointers for tile mtv (column nt) */
#define MKPTRS(mtv, A0, A1, B0, B1, TOFF, ROW0, ROWS) do {                    \
    unsigned tev = table[mtv];                                                \
    int lv = tev & 15; (ROW0) = (int)(tev >> 4);                              \
    (TOFF) = goff[lv]; (ROWS) = grows[lv];                                    \
    long re0, re1;                                                            \
    { int rg = (ROW0) + srow;                                                 \
      if (rg < (ROWS)) { unsigned e = tlist[(TOFF) + (rg >> 3)];              \
        unsigned n = (e >> 12) & 0x3FF; int b = rg & 7;                       \
        re0 = (n >= N_) ? ZROW * (long)DIN : ((long)(b * N_ + (int)n)) * DIN; \
      } else re0 = ZROW * (long)DIN; }                                        \
    { int rg = (ROW0) + 64 + srow;                                            \
      if (rg < (ROWS)) { unsigned e = tlist[(TOFF) + (rg >> 3)];              \
        unsigned n = (e >> 12) & 0x3FF; int b = rg & 7;                       \
        re1 = (n >= N_) ? ZROW * (long)DIN : ((long)(b * N_ + (int)n)) * DIN; \
      } else re1 = ZROW * (long)DIN; }                                        \
    (A0) = (const char*)(wsP + re0) + sx4;                                    \
    (A1) = (const char*)(wsP + re1) + sx4;                                    \
    (B0) = (const char*)(wsW + ((long)lv * DOUT + nt * BN + srow) * DIN) + sx4;       \
    (B1) = (const char*)(wsW + ((long)lv * DOUT + nt * BN + 64 + srow) * DIN) + sx4;  \
  } while (0)

  const char *a0c, *a1c, *b0c, *b1c;
  const char *a0n, *a1n, *b0n, *b1n;
  int toff_c, row0_c, rows_c;
  int toff_n = 0, row0_n = 0, rows_n = 0;
  MKPTRS(mt, a0c, a1c, b0c, b1c, toff_c, row0_c, rows_c);
  a0n = a0c; a1n = a1c; b0n = b0c; b1n = b1c;

#define STG_C(kt_, sb) do { \
  gload_lds16(a0c + (kt_) * 64, (char*)As[sb] + w * 1024); \
  gload_lds16(a1c + (kt_) * 64, (char*)As[sb] + 4096 + w * 1024); \
  gload_lds16(b0c + (kt_) * 64, (char*)Bs[sb] + w * 1024); \
  gload_lds16(b1c + (kt_) * 64, (char*)Bs[sb] + 4096 + w * 1024); } while (0)
#define STG_N(kt_, sb) do { \
  gload_lds16(a0n + (kt_) * 64, (char*)As[sb] + w * 1024); \
  gload_lds16(a1n + (kt_) * 64, (char*)As[sb] + 4096 + w * 1024); \
  gload_lds16(b0n + (kt_) * 64, (char*)Bs[sb] + w * 1024); \
  gload_lds16(b1n + (kt_) * 64, (char*)Bs[sb] + 4096 + w * 1024); } while (0)

  /* ---- fragment read offsets (R6/R8-verified, conflict-free) ---- */
  const int arow = wm * 64 + (lane & 15);
  const int brow = wn * 64 + (lane & 15);
  const int axr  = ((lane >> 4) ^ (((lane & 15) >> 1) & 3)) * 16;

  f32x4 acc[4][4];
  short8 af[4], bf[4];

#define VM(n_) asm volatile("s_waitcnt vmcnt(" #n_ ")" ::: "memory")
#define PH(T) do {                                                            \
    if ((T) < NKT - 3)      STG_C((T) + 3, ((T) + 3) & 3);                    \
    else if (has)           STG_N((T) - (NKT - 3), ((T) + 3) & 3);            \
    _Pragma("unroll") for (int m_ = 0; m_ < 4; ++m_)                          \
      af[m_] = *(const short8*)((const char*)As[(T) & 3] + (arow + m_ * 16) * 64 + axr); \
    _Pragma("unroll") for (int n_ = 0; n_ < 4; ++n_)                          \
      bf[n_] = *(const short8*)((const char*)Bs[(T) & 3] + (brow + n_ * 16) * 64 + axr); \
    bar();                                                                    \
    asm volatile("s_waitcnt lgkmcnt(0)" ::: "memory");                        \
    __builtin_amdgcn_s_setprio(1);                                            \
    _Pragma("unroll") for (int n_ = 0; n_ < 4; ++n_)                          \
      _Pragma("unroll") for (int m_ = 0; m_ < 4; ++m_)                        \
        acc[m_][n_] = __builtin_amdgcn_mfma_f32_16x16x32_bf16(af[m_], bf[n_], acc[m_][n_], 0, 0, 0); \
    __builtin_amdgcn_s_setprio(0);                                            \
    if ((T) < NKT - 3 || has) { VM(8); }                                      \
    else if ((T) == NKT - 3)  { VM(4); }                                      \
    else if ((T) == NKT - 2)  { VM(0); }                                      \
    bar();                                                                    \
  } while (0)

  /* ---- prologue: kt0,1,2 -> bufs 0,1,2; kt0 complete before phase 0 ---- */
  STG_C(0, 0); STG_C(1, 1); STG_C(2, 2);
  VM(8);
  bar();

  for (;;) {
    if (tid == 0) s_g = atomicAdd(&ctr[nt], 1);   /* claim next tile */
    bool has = false;

#pragma unroll
    for (int m = 0; m < 4; ++m)
#pragma unroll
      for (int n = 0; n < 4; ++n)
        acc[m][n] = (f32x4){0.f, 0.f, 0.f, 0.f};

    PH(0); PH(1); PH(2); PH(3); PH(4);
    {
      int mtn = s_g;                     /* published by phase barriers */
      has = (mtn < NT);
      if (has) MKPTRS(mtn, a0n, a1n, b0n, b1n, toff_n, row0_n, rows_n);
    }
    PH(5);  PH(6);  PH(7);  PH(8);  PH(9);  PH(10); PH(11); PH(12);
    PH(13); PH(14); PH(15); PH(16); PH(17); PH(18); PH(19); PH(20);
    PH(21); PH(22); PH(23); PH(24); PH(25); PH(26); PH(27); PH(28);
    PH(29); PH(30); PH(31);

    /* ---- epilogue: C/D col=lane&15, row=(lane>>4)*4+j; rep-write ---- */
#pragma unroll
    for (int m = 0; m < 4; ++m) {
#pragma unroll
      for (int jj = 0; jj < 4; ++jj) {
        int rt = wm * 64 + m * 16 + (lane >> 4) * 4 + jj;
        int rg = row0_c + rt;
        if (rg >= rows_c) continue;
        unsigned e = tlist[toff_c + (rg >> 3)];
        int b = rg & 7;
        int t0 = (int)(e & 0xFFFu);
        int rep = (int)(e >> 22);
        float* orow = out + ((long)b * T_ + t0) * DOUT + nt * BN + wn * 64 + (lane & 15);
        for (int r = 0; r < rep; ++r) {
#pragma unroll
          for (int n = 0; n < 4; ++n)
            orow[n * 16] = acc[m][n][jj];
          orow += DOUT;
        }
      }
    }

    if (!has) break;
    a0c = a0n; a1c = a1n; b0c = b0n; b1c = b1n;
    toff_c = toff_n; row0_c = row0_n; rows_c = rows_n;
  }
#undef PH
#undef VM
#undef STG_C
#undef STG_N
#undef MKPTRS
}

/* ---------------- launch ---------------- */
extern "C" void kernel_launch(void* const* d_in, const int* in_sizes, int n_in,
                              void* d_out, int out_size, void* d_ws, size_t ws_size,
                              hipStream_t stream) {
  const float* pooled = (const float*)d_in[0];
  const float* W      = (const float*)d_in[1];
  const int*   pidx   = (const int*)d_in[2];
  float* out = (float*)d_out;

  char* ws = (char*)d_ws;
  unsigned short* wsP = (unsigned short*)(ws);
  unsigned short* wsW = (unsigned short*)(ws + WS_W_OFF);
  int* meta  = (int*)(ws + WS_META_OFF);
  unsigned* tlist = (unsigned*)meta;
  int* goff  = meta + 8 * T_;
  int* grows = meta + 8 * T_ + 16;
  unsigned* table = (unsigned*)(meta + 8 * T_ + 32);
  int* ntiles = meta + 8 * T_ + 32 + MT_MAX;
  int* ctr    = ntiles + 1;                        /* 8 ints */

  k_prep<<<1, 512, 0, stream>>>(pidx, tlist, goff, grows, table, ntiles, ctr);
  k_convert<<<2048, 256, 0, stream>>>(pooled, W, wsP, wsW);
  k_gemm<<<GRID_GEMM, 256, 0, stream>>>(wsP, wsW, tlist, goff, grows, table,
                                        ntiles, ctr, out);
}

// Round 10
// 130.233 us; speedup vs baseline: 1.1552x; 1.1552x over previous
//
#include <hip/hip_runtime.h>
#include <stdint.h>

#define B_    8
#define N_    512
#define DIN   1024
#define DOUT  1024
#define L_    16
#define T_    4096

#define BM 128
#define BN 128
#define BK 32
#define NB (DOUT / BN)          /* 8 */
#define NKT (DIN / BK)          /* 32 K-tiles */
#define MT_MAX 288
#define ZROW ((long)B_ * N_)    /* zero-row index in pooled_bf16 */

typedef __attribute__((ext_vector_type(8))) short short8;
typedef __attribute__((ext_vector_type(4))) float f32x4;

/* ws layout: pooled_bf16 (+zero row) | W' fragment-ordered bf16 | meta */
#define POOLED_ELEMS ((long)B_ * N_ * DIN + DIN)
#define WS_W_OFF     ((size_t)POOLED_ELEMS * 2)
#define WS_META_OFF  (WS_W_OFF + (size_t)L_ * DOUT * DIN * 2)

__device__ __forceinline__ unsigned short f2bf(float f) {
  unsigned u = __float_as_uint(f);
  u += 0x7FFFu + ((u >> 16) & 1u);   /* RNE */
  return (unsigned short)(u >> 16);
}

__device__ __forceinline__ void gload_lds16(const void* g, void* l) {
  __builtin_amdgcn_global_load_lds(
      (const __attribute__((address_space(1))) void*)g,
      (__attribute__((address_space(3))) void*)l, 16, 0, 0);
}

/* ---------------- kernel 1: convert pooled->bf16, W->W' fragment order ------
   W'[l][cb][kb][lane*8]: lane ln holds W[l][cb*16 + (ln&15)][kb*32 + (ln>>4)*8
   .. +8) — exactly the 16x16x32 MFMA B-fragment, so a wave's B-frag load is
   ONE fully-coalesced 1KB global load (base + ln*16B). Wave reads of W are
   full 128B lines (kb*32 floats = one aligned line).                        */
__global__ void k_convert(const float* __restrict__ pooled,
                          const float* __restrict__ W,
                          unsigned short* __restrict__ wsP,
                          unsigned short* __restrict__ wsW2) {
  const long np4 = (long)B_ * N_ * DIN / 4;      /* pooled float4 units */
  const long nz4 = DIN / 4;                      /* zero-row units */
  const long nwu = (long)L_ * 64 * 32 * 64;      /* W' 8-elem units */
  long i = (long)blockIdx.x * blockDim.x + threadIdx.x;
  const long stride = (long)gridDim.x * blockDim.x;
  for (; i < np4 + nz4 + nwu; i += stride) {
    if (i < np4) {
      float4 v = ((const float4*)pooled)[i];
      ushort4 o = { f2bf(v.x), f2bf(v.y), f2bf(v.z), f2bf(v.w) };
      ((ushort4*)wsP)[i] = o;
    } else if (i < np4 + nz4) {
      ushort4 z = {0, 0, 0, 0};
      ((ushort4*)wsP)[i] = z;                    /* zero row right after pooled */
    } else {
      long u = i - np4 - nz4;
      int ln = (int)(u & 63); long tmp = u >> 6;
      int kb = (int)(tmp & 31); tmp >>= 5;
      int cb = (int)(tmp & 63); int l = (int)(tmp >> 6);
      int r = cb * 16 + (ln & 15);
      int k = kb * 32 + (ln >> 4) * 8;
      const float* src = W + ((long)l * DOUT + r) * DIN + k;
      float4 v0 = *(const float4*)(src);
      float4 v1 = *(const float4*)(src + 4);
      ushort4 o0 = { f2bf(v0.x), f2bf(v0.y), f2bf(v0.z), f2bf(v0.w) };
      ushort4 o1 = { f2bf(v1.x), f2bf(v1.y), f2bf(v1.z), f2bf(v1.w) };
      ((ushort4*)wsW2)[u * 2]     = o0;
      ((ushort4*)wsW2)[u * 2 + 1] = o1;
    }
  }
}

/* ---------------- kernel 2: dedup prep (verbatim R8) ---------------- */
__global__ void k_prep(const int* __restrict__ pidx,
                       unsigned* __restrict__ tlist,
                       int* __restrict__ goff, int* __restrict__ grows,
                       unsigned* __restrict__ table, int* __restrict__ ntiles) {
  __shared__ int sp[N_];
  __shared__ int cnt[L_], pos[L_];
  const int tid = threadIdx.x;
  if (tid < N_) sp[tid] = pidx[tid];
  if (tid < L_) cnt[tid] = 0;
  __syncthreads();

  int start = tid ? sp[tid - 1] + 1 : 0;
  int len = sp[tid] - start + 1;
  if (len < 0) len = 0;
  const int nfull = len < 15 ? len : 15;

  for (int l2 = 0; l2 < nfull; ++l2) atomicAdd(&cnt[l2], 1);
  if (len > 15) atomicAdd(&cnt[15], (len - 15 + 254) / 255);
  if (tid == N_ - 1) {
    int invlen = T_ - 1 - sp[N_ - 1];
    if (invlen > 0) atomicAdd(&cnt[15], (invlen + 254) / 255);
  }
  __syncthreads();
  if (tid == 0) {
    int off = 0;
    for (int l2 = 0; l2 < L_; ++l2) {
      pos[l2] = off; goff[l2] = off; grows[l2] = cnt[l2] * B_;
      off += cnt[l2];
    }
  }
  __syncthreads();

  for (int l2 = 0; l2 < nfull; ++l2) {
    int p = atomicAdd(&pos[l2], 1);
    tlist[p] = (unsigned)(start + l2) | ((unsigned)tid << 12) | (1u << 22);
  }
  if (len > 15) {
    int rem = len - 15, tt2 = start + 15;
    while (rem > 0) {
      int rr = rem > 255 ? 255 : rem;
      int p = atomicAdd(&pos[15], 1);
      tlist[p] = (unsigned)tt2 | ((unsigned)tid << 12) | ((unsigned)rr << 22);
      tt2 += rr; rem -= rr;
    }
  }
  if (tid == N_ - 1) {
    int tt2 = sp[N_ - 1] + 1;
    int rem = T_ - tt2;
    while (rem > 0) {
      int rr = rem > 255 ? 255 : rem;
      int p = atomicAdd(&pos[15], 1);
      tlist[p] = (unsigned)tt2 | (1023u << 12) | ((unsigned)rr << 22);
      tt2 += rr; rem -= rr;
    }
  }
  __syncthreads();
  if (tid == 0) {
    int tt = 0;
    for (int l2 = 0; l2 < L_; ++l2) {
      int rows = cnt[l2] * B_;
      for (int r0 = 0; r0 < rows; r0 += BM) table[tt++] = (unsigned)l2 | ((unsigned)r0 << 4);
    }
    *ntiles = tt;
  }
}

/* ---------------- kernel 3: A-via-LDS, B-direct gather-GEMM ----------------
   128x128 tile, BK=32, 4 waves (2x2), wave 64x64. A (gathered) staged via
   gload_lds into 2x8KB LDS (verified swizzle); B loaded coalesced from W'
   straight to registers (no LDS). One compiler-drained barrier per K-tile;
   2x unrolled with static bf ping-pong. 3 blocks/CU. Dedup rep-write.       */
__global__ __launch_bounds__(256, 3)
void k_gemm(const unsigned short* __restrict__ wsP,
            const unsigned short* __restrict__ wsW2,
            const unsigned* __restrict__ tlist,
            const int* __restrict__ goff,
            const int* __restrict__ grows,
            const unsigned* __restrict__ table,
            const int* __restrict__ ntiles,
            float* __restrict__ out) {
  const int bid = blockIdx.x;
  const int mt = bid >> 3;
  const int nt = bid & 7;            /* nt == XCD: W' slice pinned per L2 */
  if (mt >= *ntiles) return;

  const unsigned te = table[mt];
  const int l    = te & 15;
  const int row0 = (int)(te >> 4);
  const int toff = goff[l];
  const int rows = grows[l];

  __shared__ __align__(16) unsigned short As[2][BM * BK];  /* 2 x 8 KiB */

  const int tid  = threadIdx.x;
  const int lane = tid & 63;
  const int w    = tid >> 6;      /* 0..3 */
  const int wm   = w >> 1;
  const int wn   = w & 1;

  /* ---- A staging (verbatim R8: inverse-swizzled source slot) ---- */
  const int srow = tid >> 2;                       /* 0..63 */
  const int sx4  = ((tid & 3) ^ ((srow >> 1) & 3)) * 16;
  const char* aptr0;
  const char* aptr1;
  {
    long re[2];
#pragma unroll
    for (int r = 0; r < 2; ++r) {
      int rg = row0 + r * 64 + srow;
      if (rg < rows) {
        unsigned e = tlist[toff + (rg >> 3)];
        unsigned n = (e >> 12) & 0x3FF;
        int b = rg & 7;
        re[r] = (n >= N_) ? ZROW * (long)DIN
                          : ((long)(b * N_ + (int)n)) * DIN;
      } else re[r] = ZROW * (long)DIN;
    }
    aptr0 = (const char*)(wsP + re[0]) + sx4;
    aptr1 = (const char*)(wsP + re[1]) + sx4;
  }

#define STG_A(t_, sb) do { \
  gload_lds16(aptr0 + (t_) * 64, (char*)As[sb] + w * 1024); \
  gload_lds16(aptr1 + (t_) * 64, (char*)As[sb] + 4096 + w * 1024); } while (0)

  /* ---- A fragment read offsets (verbatim R8, conflict-free) ---- */
  const int arow = wm * 64 + (lane & 15);
  const int axr  = ((lane >> 4) ^ (((lane & 15) >> 1) & 3)) * 16;

  /* ---- B direct: W'[l][cb][kb][lane*8], cb = nt*8 + wn*4 + n ---- */
  const unsigned short* wbase =
      wsW2 + (((long)l * 64 + nt * 8 + wn * 4) * 32) * 512 + lane * 8;
#define LDB(dst, t_) do { _Pragma("unroll") \
  for (int n_ = 0; n_ < 4; ++n_) \
    dst[n_] = *(const short8*)(wbase + n_ * (32 * 512) + (t_) * 512); } while (0)

#define DSA(bb) do { _Pragma("unroll") \
  for (int m_ = 0; m_ < 4; ++m_) \
    af[m_] = *(const short8*)((const char*)As[bb] + (arow + m_ * 16) * 64 + axr); } while (0)

#define MM(BF) do { \
  __builtin_amdgcn_s_setprio(1); \
  _Pragma("unroll") for (int n_ = 0; n_ < 4; ++n_) \
    _Pragma("unroll") for (int m_ = 0; m_ < 4; ++m_) \
      acc[m_][n_] = __builtin_amdgcn_mfma_f32_16x16x32_bf16(af[m_], BF[n_], acc[m_][n_], 0, 0, 0); \
  __builtin_amdgcn_s_setprio(0); } while (0)

  f32x4 acc[4][4];
#pragma unroll
  for (int m = 0; m < 4; ++m)
#pragma unroll
    for (int n = 0; n < 4; ++n)
      acc[m][n] = (f32x4){0.f, 0.f, 0.f, 0.f};

  short8 af[4], bf_a[4], bf_b[4];

  /* ---- prologue: stage A(0)->buf0, load B(0); barrier drains both ---- */
  STG_A(0, 0);
  LDB(bf_a, 0);
  __syncthreads();

#pragma unroll
  for (int j = 0; j < NKT / 2; ++j) {
    const int t0 = 2 * j, t1 = 2 * j + 1;
    /* half 1: compute t0 from buf0; stage A(t1)->buf1, load B(t1) */
    STG_A(t1, 1);
    LDB(bf_b, t1);
    DSA(0);
    MM(bf_a);
    __syncthreads();                 /* drains stage(t1)+B(t1); reads of buf1 next */
    /* half 2: compute t1 from buf1; stage A(t0+2)->buf0, load B(t0+2) */
    if (t0 + 2 < NKT) { STG_A(t0 + 2, 0); LDB(bf_a, t0 + 2); }
    DSA(1);
    MM(bf_b);
    __syncthreads();                 /* drains stage(t0+2)+B(t0+2) */
  }

  /* ---- epilogue: C/D col=lane&15, row=(lane>>4)*4+j; rep-write ---- */
#pragma unroll
  for (int m = 0; m < 4; ++m) {
#pragma unroll
    for (int jj = 0; jj < 4; ++jj) {
      int rt = wm * 64 + m * 16 + (lane >> 4) * 4 + jj;
      int rg = row0 + rt;
      if (rg >= rows) continue;
      unsigned e = tlist[toff + (rg >> 3)];
      int b = rg & 7;
      int t0 = (int)(e & 0xFFFu);
      int rep = (int)(e >> 22);
      float* orow = out + ((long)b * T_ + t0) * DOUT + nt * BN + wn * 64 + (lane & 15);
      for (int r = 0; r < rep; ++r) {
#pragma unroll
        for (int n = 0; n < 4; ++n)
          orow[n * 16] = acc[m][n][jj];
        orow += DOUT;
      }
    }
  }
#undef STG_A
#undef LDB
#undef DSA
#undef MM
}

/* ---------------- launch ---------------- */
extern "C" void kernel_launch(void* const* d_in, const int* in_sizes, int n_in,
                              void* d_out, int out_size, void* d_ws, size_t ws_size,
                              hipStream_t stream) {
  const float* pooled = (const float*)d_in[0];
  const float* W      = (const float*)d_in[1];
  const int*   pidx   = (const int*)d_in[2];
  float* out = (float*)d_out;

  char* ws = (char*)d_ws;
  unsigned short* wsP  = (unsigned short*)(ws);
  unsigned short* wsW2 = (unsigned short*)(ws + WS_W_OFF);
  int* meta  = (int*)(ws + WS_META_OFF);
  unsigned* tlist = (unsigned*)meta;
  int* goff  = meta + 8 * T_;
  int* grows = meta + 8 * T_ + 16;
  unsigned* table = (unsigned*)(meta + 8 * T_ + 32);
  int* ntiles = meta + 8 * T_ + 32 + MT_MAX;

  k_prep<<<1, 512, 0, stream>>>(pidx, tlist, goff, grows, table, ntiles);
  k_convert<<<2048, 256, 0, stream>>>(pooled, W, wsP, wsW2);
  k_gemm<<<MT_MAX * NB, 256, 0, stream>>>(wsP, wsW2, tlist, goff, grows, table,
                                          ntiles, out);
}

// Round 11
// 127.415 us; speedup vs baseline: 1.1807x; 1.0221x over previous
//
#include <hip/hip_runtime.h>
#include <stdint.h>

#define B_    8
#define N_    512
#define DIN   1024
#define DOUT  1024
#define L_    16
#define T_    4096

#define BM 128
#define BN 128
#define BK 32
#define NB (DOUT / BN)          /* 8 */
#define NKT (DIN / BK)          /* 32 K-tiles */
#define MT_MAX 288
#define ZROW ((long)B_ * N_)    /* zero-row index in pooled_bf16 */

typedef __attribute__((ext_vector_type(8))) short short8;
typedef __attribute__((ext_vector_type(4))) float f32x4;

/* ws layout: pooled_bf16 (+zero row) | W' fragment-ordered bf16 | meta */
#define POOLED_ELEMS ((long)B_ * N_ * DIN + DIN)
#define WS_W_OFF     ((size_t)POOLED_ELEMS * 2)
#define WS_META_OFF  (WS_W_OFF + (size_t)L_ * DOUT * DIN * 2)

__device__ __forceinline__ unsigned short f2bf(float f) {
  unsigned u = __float_as_uint(f);
  u += 0x7FFFu + ((u >> 16) & 1u);   /* RNE */
  return (unsigned short)(u >> 16);
}

__device__ __forceinline__ void gload_lds16(const void* g, void* l) {
  __builtin_amdgcn_global_load_lds(
      (const __attribute__((address_space(1))) void*)g,
      (__attribute__((address_space(3))) void*)l, 16, 0, 0);
}

/* ---------------- kernel 1: convert pooled->bf16, W->W' fragment order ------
   W'[l][cb][kb][lane*8]: lane ln holds W[l][cb*16 + (ln&15)][kb*32 + (ln>>4)*8
   .. +8) — the 16x16x32 MFMA B-fragment; a wave's B-frag load is one
   coalesced 1KB global load.                                                */
__global__ void k_convert(const float* __restrict__ pooled,
                          const float* __restrict__ W,
                          unsigned short* __restrict__ wsP,
                          unsigned short* __restrict__ wsW2) {
  const long np4 = (long)B_ * N_ * DIN / 4;
  const long nz4 = DIN / 4;
  const long nwu = (long)L_ * 64 * 32 * 64;
  long i = (long)blockIdx.x * blockDim.x + threadIdx.x;
  const long stride = (long)gridDim.x * blockDim.x;
  for (; i < np4 + nz4 + nwu; i += stride) {
    if (i < np4) {
      float4 v = ((const float4*)pooled)[i];
      ushort4 o = { f2bf(v.x), f2bf(v.y), f2bf(v.z), f2bf(v.w) };
      ((ushort4*)wsP)[i] = o;
    } else if (i < np4 + nz4) {
      ushort4 z = {0, 0, 0, 0};
      ((ushort4*)wsP)[i] = z;
    } else {
      long u = i - np4 - nz4;
      int ln = (int)(u & 63); long tmp = u >> 6;
      int kb = (int)(tmp & 31); tmp >>= 5;
      int cb = (int)(tmp & 63); int l = (int)(tmp >> 6);
      int r = cb * 16 + (ln & 15);
      int k = kb * 32 + (ln >> 4) * 8;
      const float* src = W + ((long)l * DOUT + r) * DIN + k;
      float4 v0 = *(const float4*)(src);
      float4 v1 = *(const float4*)(src + 4);
      ushort4 o0 = { f2bf(v0.x), f2bf(v0.y), f2bf(v0.z), f2bf(v0.w) };
      ushort4 o1 = { f2bf(v1.x), f2bf(v1.y), f2bf(v1.z), f2bf(v1.w) };
      ((ushort4*)wsW2)[u * 2]     = o0;
      ((ushort4*)wsW2)[u * 2 + 1] = o1;
    }
  }
}

/* ---------------- kernel 2: dedup prep (verbatim R8) ---------------- */
__global__ void k_prep(const int* __restrict__ pidx,
                       unsigned* __restrict__ tlist,
                       int* __restrict__ goff, int* __restrict__ grows,
                       unsigned* __restrict__ table, int* __restrict__ ntiles) {
  __shared__ int sp[N_];
  __shared__ int cnt[L_], pos[L_];
  const int tid = threadIdx.x;
  if (tid < N_) sp[tid] = pidx[tid];
  if (tid < L_) cnt[tid] = 0;
  __syncthreads();

  int start = tid ? sp[tid - 1] + 1 : 0;
  int len = sp[tid] - start + 1;
  if (len < 0) len = 0;
  const int nfull = len < 15 ? len : 15;

  for (int l2 = 0; l2 < nfull; ++l2) atomicAdd(&cnt[l2], 1);
  if (len > 15) atomicAdd(&cnt[15], (len - 15 + 254) / 255);
  if (tid == N_ - 1) {
    int invlen = T_ - 1 - sp[N_ - 1];
    if (invlen > 0) atomicAdd(&cnt[15], (invlen + 254) / 255);
  }
  __syncthreads();
  if (tid == 0) {
    int off = 0;
    for (int l2 = 0; l2 < L_; ++l2) {
      pos[l2] = off; goff[l2] = off; grows[l2] = cnt[l2] * B_;
      off += cnt[l2];
    }
  }
  __syncthreads();

  for (int l2 = 0; l2 < nfull; ++l2) {
    int p = atomicAdd(&pos[l2], 1);
    tlist[p] = (unsigned)(start + l2) | ((unsigned)tid << 12) | (1u << 22);
  }
  if (len > 15) {
    int rem = len - 15, tt2 = start + 15;
    while (rem > 0) {
      int rr = rem > 255 ? 255 : rem;
      int p = atomicAdd(&pos[15], 1);
      tlist[p] = (unsigned)tt2 | ((unsigned)tid << 12) | ((unsigned)rr << 22);
      tt2 += rr; rem -= rr;
    }
  }
  if (tid == N_ - 1) {
    int tt2 = sp[N_ - 1] + 1;
    int rem = T_ - tt2;
    while (rem > 0) {
      int rr = rem > 255 ? 255 : rem;
      int p = atomicAdd(&pos[15], 1);
      tlist[p] = (unsigned)tt2 | (1023u << 12) | ((unsigned)rr << 22);
      tt2 += rr; rem -= rr;
    }
  }
  __syncthreads();
  if (tid == 0) {
    int tt = 0;
    for (int l2 = 0; l2 < L_; ++l2) {
      int rows = cnt[l2] * B_;
      for (int r0 = 0; r0 < rows; r0 += BM) table[tt++] = (unsigned)l2 | ((unsigned)r0 << 4);
    }
    *ntiles = tt;
  }
}

/* ---------------- kernel 3: A-via-LDS, B-direct gather-GEMM ----------------
   R10 main loop verbatim. NEW: epilogue transposes acc through padded LDS
   scratch and stores with global_store_dwordx4 — every 128B HBM line is
   written entirely by one instruction (no read-for-ownership), and rep>1
   rows become contiguous streaming writes.                                  */
__global__ __launch_bounds__(256, 3)
void k_gemm(const unsigned short* __restrict__ wsP,
            const unsigned short* __restrict__ wsW2,
            const unsigned* __restrict__ tlist,
            const int* __restrict__ goff,
            const int* __restrict__ grows,
            const unsigned* __restrict__ table,
            const int* __restrict__ ntiles,
            float* __restrict__ out) {
  const int bid = blockIdx.x;
  const int mt = bid >> 3;
  const int nt = bid & 7;            /* nt == XCD: W' slice pinned per L2 */
  if (mt >= *ntiles) return;

  const unsigned te = table[mt];
  const int l    = te & 15;
  const int row0 = (int)(te >> 4);
  const int toff = goff[l];
  const int rows = grows[l];

  __shared__ __align__(16) unsigned short As[2][BM * BK];  /* 2 x 8 KiB */
  __shared__ __align__(16) float escr[4][16 * 68];         /* 17 KiB epi scratch */

  const int tid  = threadIdx.x;
  const int lane = tid & 63;
  const int w    = tid >> 6;      /* 0..3 */
  const int wm   = w >> 1;
  const int wn   = w & 1;

  /* ---- A staging (verbatim R8: inverse-swizzled source slot) ---- */
  const int srow = tid >> 2;                       /* 0..63 */
  const int sx4  = ((tid & 3) ^ ((srow >> 1) & 3)) * 16;
  const char* aptr0;
  const char* aptr1;
  {
    long re[2];
#pragma unroll
    for (int r = 0; r < 2; ++r) {
      int rg = row0 + r * 64 + srow;
      if (rg < rows) {
        unsigned e = tlist[toff + (rg >> 3)];
        unsigned n = (e >> 12) & 0x3FF;
        int b = rg & 7;
        re[r] = (n >= N_) ? ZROW * (long)DIN
                          : ((long)(b * N_ + (int)n)) * DIN;
      } else re[r] = ZROW * (long)DIN;
    }
    aptr0 = (const char*)(wsP + re[0]) + sx4;
    aptr1 = (const char*)(wsP + re[1]) + sx4;
  }

#define STG_A(t_, sb) do { \
  gload_lds16(aptr0 + (t_) * 64, (char*)As[sb] + w * 1024); \
  gload_lds16(aptr1 + (t_) * 64, (char*)As[sb] + 4096 + w * 1024); } while (0)

  /* ---- A fragment read offsets (verbatim R8, conflict-free) ---- */
  const int arow = wm * 64 + (lane & 15);
  const int axr  = ((lane >> 4) ^ (((lane & 15) >> 1) & 3)) * 16;

  /* ---- B direct: W'[l][cb][kb][lane*8], cb = nt*8 + wn*4 + n ---- */
  const unsigned short* wbase =
      wsW2 + (((long)l * 64 + nt * 8 + wn * 4) * 32) * 512 + lane * 8;
#define LDB(dst, t_) do { _Pragma("unroll") \
  for (int n_ = 0; n_ < 4; ++n_) \
    dst[n_] = *(const short8*)(wbase + n_ * (32 * 512) + (t_) * 512); } while (0)

#define DSA(bb) do { _Pragma("unroll") \
  for (int m_ = 0; m_ < 4; ++m_) \
    af[m_] = *(const short8*)((const char*)As[bb] + (arow + m_ * 16) * 64 + axr); } while (0)

#define MM(BF) do { \
  __builtin_amdgcn_s_setprio(1); \
  _Pragma("unroll") for (int n_ = 0; n_ < 4; ++n_) \
    _Pragma("unroll") for (int m_ = 0; m_ < 4; ++m_) \
      acc[m_][n_] = __builtin_amdgcn_mfma_f32_16x16x32_bf16(af[m_], BF[n_], acc[m_][n_], 0, 0, 0); \
  __builtin_amdgcn_s_setprio(0); } while (0)

  f32x4 acc[4][4];
#pragma unroll
  for (int m = 0; m < 4; ++m)
#pragma unroll
    for (int n = 0; n < 4; ++n)
      acc[m][n] = (f32x4){0.f, 0.f, 0.f, 0.f};

  short8 af[4], bf_a[4], bf_b[4];

  /* ---- prologue ---- */
  STG_A(0, 0);
  LDB(bf_a, 0);
  __syncthreads();

#pragma unroll
  for (int j = 0; j < NKT / 2; ++j) {
    const int t0 = 2 * j, t1 = 2 * j + 1;
    STG_A(t1, 1);
    LDB(bf_b, t1);
    DSA(0);
    MM(bf_a);
    __syncthreads();
    if (t0 + 2 < NKT) { STG_A(t0 + 2, 0); LDB(bf_a, t0 + 2); }
    DSA(1);
    MM(bf_b);
    __syncthreads();
  }

  /* ---- epilogue: full-line coalesced stores via LDS transpose ----
     Per wave, per m: scatter 16x64 acc slab into padded scratch
     (stride 68 dwords), read back 4 rows/instr as lane-contiguous 16B,
     store global_store_dwordx4: 4 x 256B full lines per instruction.
     Rows in one instr share one tlist entry (same t, b=rg&7 varies);
     rep>1 rows stream contiguously t..t+rep-1.                        */
  {
    float* sc = escr[w];
#pragma unroll
    for (int m = 0; m < 4; ++m) {
#pragma unroll
      for (int n = 0; n < 4; ++n)
#pragma unroll
        for (int jj = 0; jj < 4; ++jj)
          sc[((lane >> 4) * 4 + jj) * 68 + n * 16 + (lane & 15)] = acc[m][n][jj];
      asm volatile("s_waitcnt lgkmcnt(0)" ::: "memory");
#pragma unroll
      for (int r0 = 0; r0 < 16; r0 += 4) {
        int rtl = r0 + (lane >> 4);
        float4 v = *(const float4*)(sc + rtl * 68 + (lane & 15) * 4);
        int rg = row0 + wm * 64 + m * 16 + rtl;
        if (rg < rows) {
          unsigned e = tlist[toff + (rg >> 3)];
          int b = rg & 7;
          int tt = (int)(e & 0xFFFu);
          int rep = (int)(e >> 22);
          float* p = out + ((long)b * T_ + tt) * DOUT + nt * BN + wn * 64 + (lane & 15) * 4;
          for (int r = 0; r < rep; ++r) { *(float4*)p = v; p += DOUT; }
        }
      }
      asm volatile("s_waitcnt lgkmcnt(0)" ::: "memory");
    }
  }
#undef STG_A
#undef LDB
#undef DSA
#undef MM
}

/* ---------------- launch ---------------- */
extern "C" void kernel_launch(void* const* d_in, const int* in_sizes, int n_in,
                              void* d_out, int out_size, void* d_ws, size_t ws_size,
                              hipStream_t stream) {
  const float* pooled = (const float*)d_in[0];
  const float* W      = (const float*)d_in[1];
  const int*   pidx   = (const int*)d_in[2];
  float* out = (float*)d_out;

  char* ws = (char*)d_ws;
  unsigned short* wsP  = (unsigned short*)(ws);
  unsigned short* wsW2 = (unsigned short*)(ws + WS_W_OFF);
  int* meta  = (int*)(ws + WS_META_OFF);
  unsigned* tlist = (unsigned*)meta;
  int* goff  = meta + 8 * T_;
  int* grows = meta + 8 * T_ + 16;
  unsigned* table = (unsigned*)(meta + 8 * T_ + 32);
  int* ntiles = meta + 8 * T_ + 32 + MT_MAX;

  k_prep<<<1, 512, 0, stream>>>(pidx, tlist, goff, grows, table, ntiles);
  k_convert<<<2048, 256, 0, stream>>>(pooled, W, wsP, wsW2);
  k_gemm<<<MT_MAX * NB, 256, 0, stream>>>(wsP, wsW2, tlist, goff, grows, table,
                                          ntiles, out);
}